// Round 15
// baseline (357.502 us; speedup 1.0000x reference)
//
#include <hip/hip_runtime.h>

namespace {

constexpr int D  = 64;
constexpr int S  = 2048;
constexpr int BQ = 64;    // q rows per block (4 waves x 16)
constexpr int BK = 64;    // kv rows per tile
constexpr int NT = S / BK;
constexpr float SCALE = 0.125f;  // 1/sqrt(64)
constexpr int PP = 72;    // LDS pitch for P (bf16 elems)

typedef short s16x8 __attribute__((ext_vector_type(8)));
typedef float f32x4 __attribute__((ext_vector_type(4)));

__device__ inline unsigned cvt_pk_bf16(float a, float b) {   // lo=bf16(a), hi=bf16(b), RNE
  unsigned r;
  asm("v_cvt_pk_bf16_f32 %0, %1, %2" : "=v"(r) : "v"(a), "v"(b));
  return r;
}

__device__ inline unsigned short f2bf(float f) {
  union { float f; unsigned u; } v; v.f = f;
  unsigned u = v.u + (0x7fffu + ((v.u >> 16) & 1u));  // RNE
  return (unsigned short)(u >> 16);
}

// ---- one-shot: K -> bf16 [bh][k][d]; V -> bf16 transposed [bh][d][k] ----
__global__ __launch_bounds__(256)
void cvt_kv(const float* __restrict__ Kg, const float* __restrict__ Vg,
            unsigned short* __restrict__ Kw, unsigned short* __restrict__ Vw)
{
  __shared__ unsigned short vt[64 * 72];
  const int tid = threadIdx.x;
  const int kt = blockIdx.x, bh = blockIdx.y;
  const int k0 = kt * BK;

  #pragma unroll
  for (int i = 0; i < 4; ++i) {
    const int e4 = i * 256 + tid;
    const int r  = e4 >> 4;          // kv row within tile 0..63
    const int db = (e4 & 15) * 4;    // d base 0..60
    const size_t rowK = (size_t)bh * S + k0 + r;

    const float4 kf = *(const float4*)(Kg + rowK * D + db);
    const float4 vf = *(const float4*)(Vg + rowK * D + db);

    uint2 kk;
    kk.x = cvt_pk_bf16(kf.x, kf.y);
    kk.y = cvt_pk_bf16(kf.z, kf.w);
    *(uint2*)&Kw[rowK * D + db] = kk;   // coalesced, logical layout

    const unsigned v01 = cvt_pk_bf16(vf.x, vf.y);
    const unsigned v23 = cvt_pk_bf16(vf.z, vf.w);
    vt[(db + 0) * 72 + r] = (unsigned short)(v01);
    vt[(db + 1) * 72 + r] = (unsigned short)(v01 >> 16);
    vt[(db + 2) * 72 + r] = (unsigned short)(v23);
    vt[(db + 3) * 72 + r] = (unsigned short)(v23 >> 16);
  }
  __syncthreads();

  const int d  = tid >> 2;          // 0..63
  const int bq = (tid & 3) * 16;    // 16 ushorts per thread
  const uint4 a = *(const uint4*)&vt[d * 72 + bq];
  const uint4 b = *(const uint4*)&vt[d * 72 + bq + 8];
  unsigned short* vrow = Vw + ((size_t)bh * D + d) * S + k0 + bq;
  *(uint4*)(vrow)     = a;
  *(uint4*)(vrow + 8) = b;
}

// ---- bit-pack the int32 mask: Mb[bh][q][kt] = 64 mask bits (bit i => k = kt*64+i) ----
// One block per (q, bh) row; fully coalesced 8 KB sequential read, 256 B write.
__global__ __launch_bounds__(256)
void mask_bits(const int* __restrict__ Mg, unsigned long long* __restrict__ Mb)
{
  const int q    = blockIdx.x;
  const int bh   = blockIdx.y;
  const int lane = threadIdx.x & 63;
  const int w    = threadIdx.x >> 6;
  const int* Mrow = Mg + ((size_t)bh * S + q) * S;
  unsigned long long* Mbrow = Mb + ((size_t)bh * S + q) * NT;

  #pragma unroll
  for (int i = 0; i < 2; ++i) {
    const int base = (w + 4 * i) * 256;             // int offset; wave covers 1 KB contiguous
    const uint4 v = *(const uint4*)(Mrow + base + lane * 4);
    unsigned long long word =
        ((v.x ? 1ull : 0ull) | (v.y ? 2ull : 0ull) |
         (v.z ? 4ull : 0ull) | (v.w ? 8ull : 0ull)) << (4 * (lane & 15));
    // OR-reduce across each 16-lane group -> every lane holds the full 64-bit word
    word |= __shfl_xor(word, 1);
    word |= __shfl_xor(word, 2);
    word |= __shfl_xor(word, 4);
    word |= __shfl_xor(word, 8);
    if ((lane & 15) == 0)
      Mbrow[(base >> 6) + (lane >> 4)] = word;      // 4 lanes write 32 B contiguous
  }
}

// ---- main attention (R9 champion base; delta: 8-byte bit-mask per tile) ----
__global__ __launch_bounds__(256, 4)
void attn_fwd(const float* __restrict__ Qg,
              const unsigned short* __restrict__ Kw,
              const unsigned short* __restrict__ Vw,
              const unsigned long long* __restrict__ Mb,
              float* __restrict__ Og)
{
  __shared__ unsigned short k_lds[BK * 64];     // [k][d] bf16, 16B-blocks XOR-swizzled by (k&7)
  __shared__ unsigned short vt_lds[D * 64];     // [d][k] bf16, swizzled by (d&7)
  __shared__ unsigned short p_lds[4 * 16 * PP]; // per-wave P [q16][k64]

  const int tid  = threadIdx.x;
  const int lane = tid & 63;
  const int w    = tid >> 6;
  const int g    = lane >> 4;
  const int lq   = lane & 15;

  const int q0 = blockIdx.x * BQ;
  const int bh = blockIdx.y;

  const float* Qb = Qg + (size_t)bh * S * D;
  float* Ob = Og + (size_t)bh * S * D;
  const unsigned short* Kb = Kw + (size_t)bh * S * D;
  const unsigned short* Vb = Vw + (size_t)bh * D * S;
  // this lane's q-row bit-mask words, one 8-B word per k-tile
  const unsigned long long* Mrow = Mb + ((size_t)bh * S + (q0 + w * 16 + lq)) * NT;

  // staging assignment: thread -> row sr (0..63), block pair sb (0,2,4,6)
  const int sr  = tid >> 2;
  const int sb  = (tid & 3) * 2;
  const int swz = sr & 7;
  const unsigned short* Ksrc0 = Kb + (size_t)sr * D + sb * 8;          // + k0*64 per tile
  const unsigned short* Vsrc0 = Vb + (size_t)sr * S + sb * 8;          // + k0 per tile

  // Q fragments (B-operand): q = q0+w*16+lq, d = ks*32+g*8+j; scale folded in
  s16x8 qf[2];
  {
    const float* qr = Qb + (size_t)(q0 + w * 16 + lq) * D;
    #pragma unroll
    for (int ks = 0; ks < 2; ++ks) {
      float4 a = *(const float4*)(qr + ks * 32 + g * 8);
      float4 b = *(const float4*)(qr + ks * 32 + g * 8 + 4);
      s16x8 t;
      t[0] = (short)f2bf(a.x * SCALE); t[1] = (short)f2bf(a.y * SCALE);
      t[2] = (short)f2bf(a.z * SCALE); t[3] = (short)f2bf(a.w * SCALE);
      t[4] = (short)f2bf(b.x * SCALE); t[5] = (short)f2bf(b.y * SCALE);
      t[6] = (short)f2bf(b.z * SCALE); t[7] = (short)f2bf(b.w * SCALE);
      qf[ks] = t;
    }
  }

  f32x4 o[4];
  #pragma unroll
  for (int i = 0; i < 4; ++i) { o[i][0]=0.f; o[i][1]=0.f; o[i][2]=0.f; o[i][3]=0.f; }
  float m_run = -INFINITY, l_run = 0.f;

  unsigned short* p_w = p_lds + w * 16 * PP;
  const int swzr = lq & 7;   // read-side swizzle (rows step by 16 so row&7 == lq&7)

  // ---- prologue: tile-0 KV staging regs + tile-0 mask word ----
  uint4 ka = *(const uint4*)(Ksrc0);
  uint4 kb = *(const uint4*)(Ksrc0 + 8);
  uint4 va = *(const uint4*)(Vsrc0);
  uint4 vb = *(const uint4*)(Vsrc0 + 8);
  unsigned long long mw = Mrow[0];

  for (int kt = 0; kt < NT; ++kt) {
    // ---- write-late: regs staged one full tile ago -> LDS ----
    *(uint4*)&k_lds [sr * 64 + ((sb    ) ^ swz) * 8] = ka;
    *(uint4*)&k_lds [sr * 64 + ((sb + 1) ^ swz) * 8] = kb;
    *(uint4*)&vt_lds[sr * 64 + ((sb    ) ^ swz) * 8] = va;
    *(uint4*)&vt_lds[sr * 64 + ((sb + 1) ^ swz) * 8] = vb;

    // barrier-1 (write->read): drain LDS only, NOT vmem
    asm volatile("s_waitcnt lgkmcnt(0)" ::: "memory");
    __builtin_amdgcn_sched_barrier(0);
    __builtin_amdgcn_s_barrier();

    // ---- issue-early: tile kt+1 KV + mask-word loads; land during this tile's compute ----
    const int kn = (kt + 1 < NT) ? (kt + 1) * BK : kt * BK;
    uint4 kan = *(const uint4*)(Ksrc0 + (size_t)kn * 64);
    uint4 kbn = *(const uint4*)(Ksrc0 + (size_t)kn * 64 + 8);
    uint4 van = *(const uint4*)(Vsrc0 + kn);
    uint4 vbn = *(const uint4*)(Vsrc0 + kn + 8);
    unsigned long long mwn = Mrow[kn >> 6];

    // ---- S^T = K . Q^T  (C[k][q]) ----
    f32x4 st[4];
    #pragma unroll
    for (int t = 0; t < 4; ++t) {
      f32x4 c; c[0]=0.f; c[1]=0.f; c[2]=0.f; c[3]=0.f;
      #pragma unroll
      for (int ks = 0; ks < 2; ++ks) {
        s16x8 a = *(const s16x8*)&k_lds[(16 * t + lq) * 64 + (((ks << 2) + g) ^ swzr) * 8];
        c = __builtin_amdgcn_mfma_f32_16x16x32_bf16(a, qf[ks], c, 0, 0, 0);
      }
      st[t] = c;
    }

    // ---- mask (bits 16t+4g+r of mw) + online softmax; lane owns q=w*16+lq ----
    const unsigned mlo = (unsigned)mw;
    const unsigned mhi = (unsigned)(mw >> 32);
    float mx = -INFINITY;
    #pragma unroll
    for (int t = 0; t < 4; ++t) {
      const unsigned nib = ((t < 2 ? mlo : mhi) >> (16 * (t & 1) + 4 * g)) & 0xFu;
      if (nib & 1u) st[t][0] = -1e9f;
      if (nib & 2u) st[t][1] = -1e9f;
      if (nib & 4u) st[t][2] = -1e9f;
      if (nib & 8u) st[t][3] = -1e9f;
      mx = fmaxf(mx, fmaxf(fmaxf(st[t][0], st[t][1]), fmaxf(st[t][2], st[t][3])));
    }
    mx = fmaxf(mx, __shfl_xor(mx, 16));
    mx = fmaxf(mx, __shfl_xor(mx, 32));
    const float m_new = fmaxf(m_run, mx);
    const float alpha = __expf(m_run - m_new);
    float rs = 0.f;
    #pragma unroll
    for (int t = 0; t < 4; ++t) {
      #pragma unroll
      for (int r = 0; r < 4; ++r) {
        float p = __expf(st[t][r] - m_new);
        st[t][r] = p;
        rs += p;
      }
    }
    rs += __shfl_xor(rs, 16);
    rs += __shfl_xor(rs, 32);
    l_run = l_run * alpha + rs;
    m_run = m_new;

    const float al0 = __shfl(alpha, 4 * g + 0);
    const float al1 = __shfl(alpha, 4 * g + 1);
    const float al2 = __shfl(alpha, 4 * g + 2);
    const float al3 = __shfl(alpha, 4 * g + 3);
    #pragma unroll
    for (int dt = 0; dt < 4; ++dt) {
      o[dt][0] *= al0; o[dt][1] *= al1; o[dt][2] *= al2; o[dt][3] *= al3;
    }

    // ---- P -> per-wave LDS (bf16 via cvt_pk) ----
    #pragma unroll
    for (int t = 0; t < 4; ++t) {
      uint2 pk;
      pk.x = cvt_pk_bf16(st[t][0], st[t][1]);
      pk.y = cvt_pk_bf16(st[t][2], st[t][3]);
      *(uint2*)&p_w[lq * PP + 16 * t + 4 * g] = pk;
    }
    asm volatile("s_waitcnt lgkmcnt(0)" ::: "memory");  // wave-local P RAW
    __builtin_amdgcn_sched_barrier(0);

    // ---- O += P . V ----
    const s16x8 pa0 = *(const s16x8*)&p_w[lq * PP + 0  + g * 8];
    const s16x8 pa1 = *(const s16x8*)&p_w[lq * PP + 32 + g * 8];
    #pragma unroll
    for (int dt = 0; dt < 4; ++dt) {
      s16x8 vb0 = *(const s16x8*)&vt_lds[(16 * dt + lq) * 64 + ((g    ) ^ swzr) * 8];
      s16x8 vb1 = *(const s16x8*)&vt_lds[(16 * dt + lq) * 64 + ((4 + g) ^ swzr) * 8];
      o[dt] = __builtin_amdgcn_mfma_f32_16x16x32_bf16(pa0, vb0, o[dt], 0, 0, 0);
      o[dt] = __builtin_amdgcn_mfma_f32_16x16x32_bf16(pa1, vb1, o[dt], 0, 0, 0);
    }

    // barrier-2 (read->write WAR before next iter's ds_write)
    __builtin_amdgcn_s_barrier();

    ka = kan; kb = kbn; va = van; vb = vbn;
    mw = mwn;
  }

  // ---- epilogue ----
  const float linv = 1.0f / l_run;
  const float li0 = __shfl(linv, 4 * g + 0);
  const float li1 = __shfl(linv, 4 * g + 1);
  const float li2 = __shfl(linv, 4 * g + 2);
  const float li3 = __shfl(linv, 4 * g + 3);
  #pragma unroll
  for (int dt = 0; dt < 4; ++dt) {
    const int d = 16 * dt + lq;
    Ob[(size_t)(q0 + w * 16 + 4 * g + 0) * D + d] = o[dt][0] * li0;
    Ob[(size_t)(q0 + w * 16 + 4 * g + 1) * D + d] = o[dt][1] * li1;
    Ob[(size_t)(q0 + w * 16 + 4 * g + 2) * D + d] = o[dt][2] * li2;
    Ob[(size_t)(q0 + w * 16 + 4 * g + 3) * D + d] = o[dt][3] * li3;
  }
}

} // namespace

extern "C" void kernel_launch(void* const* d_in, const int* in_sizes, int n_in,
                              void* d_out, int out_size, void* d_ws, size_t ws_size,
                              hipStream_t stream) {
  const float* Q = (const float*)d_in[0];
  const float* K = (const float*)d_in[1];
  const float* V = (const float*)d_in[2];
  const int*   M = (const int*)d_in[3];
  float* O = (float*)d_out;

  unsigned short* Kw = (unsigned short*)d_ws;                 // 16.78 MB
  unsigned short* Vw = Kw + (size_t)4 * 16 * S * D;           // 16.78 MB (V^T)
  unsigned long long* Mb =
      (unsigned long long*)(Vw + (size_t)4 * 16 * S * D);     // 33.5 MB bit-mask

  dim3 cgrid(NT, 4 * 16);
  hipLaunchKernelGGL(cvt_kv, cgrid, dim3(256), 0, stream, K, V, Kw, Vw);

  dim3 mgrid(S, 4 * 16);   // one block per (q, bh) mask row
  hipLaunchKernelGGL(mask_bits, mgrid, dim3(256), 0, stream, M, Mb);

  dim3 grid(S / BQ, 4 * 16);
  hipLaunchKernelGGL(attn_fwd, grid, dim3(256), 0, stream, Q, Kw, Vw, Mb, O);
}

// Round 16
// 297.463 us; speedup vs baseline: 1.2018x; 1.2018x over previous
//
#include <hip/hip_runtime.h>

namespace {

constexpr int D  = 64;
constexpr int S  = 2048;
constexpr int BQ = 64;    // q rows per block (4 waves x 16)
constexpr int BK = 64;    // kv rows per tile
constexpr int NT = S / BK;
constexpr float SCALE = 0.125f;  // 1/sqrt(64)
constexpr int PP = 72;    // LDS pitch for P (bf16 elems)

typedef short s16x8 __attribute__((ext_vector_type(8)));
typedef float f32x4 __attribute__((ext_vector_type(4)));

__device__ inline unsigned cvt_pk_bf16(float a, float b) {   // lo=bf16(a), hi=bf16(b), RNE
  unsigned r;
  asm("v_cvt_pk_bf16_f32 %0, %1, %2" : "=v"(r) : "v"(a), "v"(b));
  return r;
}

__device__ inline unsigned short f2bf(float f) {
  union { float f; unsigned u; } v; v.f = f;
  unsigned u = v.u + (0x7fffu + ((v.u >> 16) & 1u));  // RNE
  return (unsigned short)(u >> 16);
}

// ---- one-shot: K -> bf16 [bh][k][d]; V -> bf16 transposed [bh][d][k] ----
__global__ __launch_bounds__(256)
void cvt_kv(const float* __restrict__ Kg, const float* __restrict__ Vg,
            unsigned short* __restrict__ Kw, unsigned short* __restrict__ Vw)
{
  __shared__ unsigned short vt[64 * 72];
  const int tid = threadIdx.x;
  const int kt = blockIdx.x, bh = blockIdx.y;
  const int k0 = kt * BK;

  #pragma unroll
  for (int i = 0; i < 4; ++i) {
    const int e4 = i * 256 + tid;
    const int r  = e4 >> 4;          // kv row within tile 0..63
    const int db = (e4 & 15) * 4;    // d base 0..60
    const size_t rowK = (size_t)bh * S + k0 + r;

    const float4 kf = *(const float4*)(Kg + rowK * D + db);
    const float4 vf = *(const float4*)(Vg + rowK * D + db);

    uint2 kk;
    kk.x = cvt_pk_bf16(kf.x, kf.y);
    kk.y = cvt_pk_bf16(kf.z, kf.w);
    *(uint2*)&Kw[rowK * D + db] = kk;   // coalesced, logical layout

    const unsigned v01 = cvt_pk_bf16(vf.x, vf.y);
    const unsigned v23 = cvt_pk_bf16(vf.z, vf.w);
    vt[(db + 0) * 72 + r] = (unsigned short)(v01);
    vt[(db + 1) * 72 + r] = (unsigned short)(v01 >> 16);
    vt[(db + 2) * 72 + r] = (unsigned short)(v23);
    vt[(db + 3) * 72 + r] = (unsigned short)(v23 >> 16);
  }
  __syncthreads();

  const int d  = tid >> 2;          // 0..63
  const int bq = (tid & 3) * 16;    // 16 ushorts per thread
  const uint4 a = *(const uint4*)&vt[d * 72 + bq];
  const uint4 b = *(const uint4*)&vt[d * 72 + bq + 8];
  unsigned short* vrow = Vw + ((size_t)bh * D + d) * S + k0 + bq;
  *(uint4*)(vrow)     = a;
  *(uint4*)(vrow + 8) = b;
}

// ---- main attention (R9 champion; single delta: s_setprio around MFMA clusters) ----
__global__ __launch_bounds__(256, 4)
void attn_fwd(const float* __restrict__ Qg,
              const unsigned short* __restrict__ Kw,
              const unsigned short* __restrict__ Vw,
              const int* __restrict__ Mg,
              float* __restrict__ Og)
{
  __shared__ unsigned short k_lds[BK * 64];     // [k][d] bf16, 16B-blocks XOR-swizzled by (k&7)
  __shared__ unsigned short vt_lds[D * 64];     // [d][k] bf16, swizzled by (d&7)
  __shared__ unsigned short p_lds[4 * 16 * PP]; // per-wave P [q16][k64]

  const int tid  = threadIdx.x;
  const int lane = tid & 63;
  const int w    = tid >> 6;
  const int g    = lane >> 4;
  const int lq   = lane & 15;

  const int q0 = blockIdx.x * BQ;
  const int bh = blockIdx.y;

  const float* Qb = Qg + (size_t)bh * S * D;
  float* Ob = Og + (size_t)bh * S * D;
  const unsigned short* Kb = Kw + (size_t)bh * S * D;
  const unsigned short* Vb = Vw + (size_t)bh * D * S;
  const int* Mq = Mg + (size_t)bh * S * S + (size_t)(q0 + w * 16 + lq) * S;

  // staging assignment: thread -> row sr (0..63), block pair sb (0,2,4,6)
  const int sr  = tid >> 2;
  const int sb  = (tid & 3) * 2;
  const int swz = sr & 7;
  const unsigned short* Ksrc0 = Kb + (size_t)sr * D + sb * 8;          // + k0*64 per tile
  const unsigned short* Vsrc0 = Vb + (size_t)sr * S + sb * 8;          // + k0 per tile

  // Q fragments (B-operand): q = q0+w*16+lq, d = ks*32+g*8+j; scale folded in
  s16x8 qf[2];
  {
    const float* qr = Qb + (size_t)(q0 + w * 16 + lq) * D;
    #pragma unroll
    for (int ks = 0; ks < 2; ++ks) {
      float4 a = *(const float4*)(qr + ks * 32 + g * 8);
      float4 b = *(const float4*)(qr + ks * 32 + g * 8 + 4);
      s16x8 t;
      t[0] = (short)f2bf(a.x * SCALE); t[1] = (short)f2bf(a.y * SCALE);
      t[2] = (short)f2bf(a.z * SCALE); t[3] = (short)f2bf(a.w * SCALE);
      t[4] = (short)f2bf(b.x * SCALE); t[5] = (short)f2bf(b.y * SCALE);
      t[6] = (short)f2bf(b.z * SCALE); t[7] = (short)f2bf(b.w * SCALE);
      qf[ks] = t;
    }
  }

  f32x4 o[4];
  #pragma unroll
  for (int i = 0; i < 4; ++i) { o[i][0]=0.f; o[i][1]=0.f; o[i][2]=0.f; o[i][3]=0.f; }
  float m_run = -INFINITY, l_run = 0.f;

  unsigned short* p_w = p_lds + w * 16 * PP;
  const int swzr = lq & 7;   // read-side swizzle (rows step by 16 so row&7 == lq&7)

  // ---- prologue: tile-0 KV staging regs + tile-0 mask ----
  uint4 ka = *(const uint4*)(Ksrc0);
  uint4 kb = *(const uint4*)(Ksrc0 + 8);
  uint4 va = *(const uint4*)(Vsrc0);
  uint4 vb = *(const uint4*)(Vsrc0 + 8);
  uint4 mw[4];
  #pragma unroll
  for (int t = 0; t < 4; ++t) mw[t] = *(const uint4*)(Mq + 16 * t + 4 * g);

  for (int kt = 0; kt < NT; ++kt) {
    // ---- write-late: regs staged one full tile ago -> LDS ----
    *(uint4*)&k_lds [sr * 64 + ((sb    ) ^ swz) * 8] = ka;
    *(uint4*)&k_lds [sr * 64 + ((sb + 1) ^ swz) * 8] = kb;
    *(uint4*)&vt_lds[sr * 64 + ((sb    ) ^ swz) * 8] = va;
    *(uint4*)&vt_lds[sr * 64 + ((sb + 1) ^ swz) * 8] = vb;

    // barrier-1 (write->read): drain LDS only, NOT vmem
    asm volatile("s_waitcnt lgkmcnt(0)" ::: "memory");
    __builtin_amdgcn_sched_barrier(0);
    __builtin_amdgcn_s_barrier();

    // ---- issue-early: tile kt+1 KV + mask loads; land during this tile's compute ----
    const int kn = (kt + 1 < NT) ? (kt + 1) * BK : kt * BK;
    uint4 kan = *(const uint4*)(Ksrc0 + (size_t)kn * 64);
    uint4 kbn = *(const uint4*)(Ksrc0 + (size_t)kn * 64 + 8);
    uint4 van = *(const uint4*)(Vsrc0 + kn);
    uint4 vbn = *(const uint4*)(Vsrc0 + kn + 8);
    uint4 mwn[4];
    #pragma unroll
    for (int t = 0; t < 4; ++t) mwn[t] = *(const uint4*)(Mq + kn + 16 * t + 4 * g);

    // ---- S^T = K . Q^T  (C[k][q]); prioritized MFMA burst (T5) ----
    __builtin_amdgcn_s_setprio(1);
    f32x4 st[4];
    #pragma unroll
    for (int t = 0; t < 4; ++t) {
      f32x4 c; c[0]=0.f; c[1]=0.f; c[2]=0.f; c[3]=0.f;
      #pragma unroll
      for (int ks = 0; ks < 2; ++ks) {
        s16x8 a = *(const s16x8*)&k_lds[(16 * t + lq) * 64 + (((ks << 2) + g) ^ swzr) * 8];
        c = __builtin_amdgcn_mfma_f32_16x16x32_bf16(a, qf[ks], c, 0, 0, 0);
      }
      st[t] = c;
    }
    __builtin_amdgcn_s_setprio(0);

    // ---- mask + online softmax; lane owns q=w*16+lq, k = 16t+4g+r ----
    float mx = -INFINITY;
    #pragma unroll
    for (int t = 0; t < 4; ++t) {
      if (mw[t].x) st[t][0] = -1e9f;
      if (mw[t].y) st[t][1] = -1e9f;
      if (mw[t].z) st[t][2] = -1e9f;
      if (mw[t].w) st[t][3] = -1e9f;
      mx = fmaxf(mx, fmaxf(fmaxf(st[t][0], st[t][1]), fmaxf(st[t][2], st[t][3])));
    }
    mx = fmaxf(mx, __shfl_xor(mx, 16));
    mx = fmaxf(mx, __shfl_xor(mx, 32));
    const float m_new = fmaxf(m_run, mx);
    const float alpha = __expf(m_run - m_new);
    float rs = 0.f;
    #pragma unroll
    for (int t = 0; t < 4; ++t) {
      #pragma unroll
      for (int r = 0; r < 4; ++r) {
        float p = __expf(st[t][r] - m_new);
        st[t][r] = p;
        rs += p;
      }
    }
    rs += __shfl_xor(rs, 16);
    rs += __shfl_xor(rs, 32);
    l_run = l_run * alpha + rs;
    m_run = m_new;

    const float al0 = __shfl(alpha, 4 * g + 0);
    const float al1 = __shfl(alpha, 4 * g + 1);
    const float al2 = __shfl(alpha, 4 * g + 2);
    const float al3 = __shfl(alpha, 4 * g + 3);
    #pragma unroll
    for (int dt = 0; dt < 4; ++dt) {
      o[dt][0] *= al0; o[dt][1] *= al1; o[dt][2] *= al2; o[dt][3] *= al3;
    }

    // ---- P -> per-wave LDS (bf16 via cvt_pk) ----
    #pragma unroll
    for (int t = 0; t < 4; ++t) {
      uint2 pk;
      pk.x = cvt_pk_bf16(st[t][0], st[t][1]);
      pk.y = cvt_pk_bf16(st[t][2], st[t][3]);
      *(uint2*)&p_w[lq * PP + 16 * t + 4 * g] = pk;
    }
    asm volatile("s_waitcnt lgkmcnt(0)" ::: "memory");  // wave-local P RAW
    __builtin_amdgcn_sched_barrier(0);

    // ---- O += P . V; prioritized MFMA burst (T5) ----
    __builtin_amdgcn_s_setprio(1);
    const s16x8 pa0 = *(const s16x8*)&p_w[lq * PP + 0  + g * 8];
    const s16x8 pa1 = *(const s16x8*)&p_w[lq * PP + 32 + g * 8];
    #pragma unroll
    for (int dt = 0; dt < 4; ++dt) {
      s16x8 vb0 = *(const s16x8*)&vt_lds[(16 * dt + lq) * 64 + ((g    ) ^ swzr) * 8];
      s16x8 vb1 = *(const s16x8*)&vt_lds[(16 * dt + lq) * 64 + ((4 + g) ^ swzr) * 8];
      o[dt] = __builtin_amdgcn_mfma_f32_16x16x32_bf16(pa0, vb0, o[dt], 0, 0, 0);
      o[dt] = __builtin_amdgcn_mfma_f32_16x16x32_bf16(pa1, vb1, o[dt], 0, 0, 0);
    }
    __builtin_amdgcn_s_setprio(0);

    // barrier-2 (read->write WAR before next iter's ds_write)
    __builtin_amdgcn_s_barrier();

    ka = kan; kb = kbn; va = van; vb = vbn;
    #pragma unroll
    for (int t = 0; t < 4; ++t) mw[t] = mwn[t];
  }

  // ---- epilogue ----
  const float linv = 1.0f / l_run;
  const float li0 = __shfl(linv, 4 * g + 0);
  const float li1 = __shfl(linv, 4 * g + 1);
  const float li2 = __shfl(linv, 4 * g + 2);
  const float li3 = __shfl(linv, 4 * g + 3);
  #pragma unroll
  for (int dt = 0; dt < 4; ++dt) {
    const int d = 16 * dt + lq;
    Ob[(size_t)(q0 + w * 16 + 4 * g + 0) * D + d] = o[dt][0] * li0;
    Ob[(size_t)(q0 + w * 16 + 4 * g + 1) * D + d] = o[dt][1] * li1;
    Ob[(size_t)(q0 + w * 16 + 4 * g + 2) * D + d] = o[dt][2] * li2;
    Ob[(size_t)(q0 + w * 16 + 4 * g + 3) * D + d] = o[dt][3] * li3;
  }
}

} // namespace

extern "C" void kernel_launch(void* const* d_in, const int* in_sizes, int n_in,
                              void* d_out, int out_size, void* d_ws, size_t ws_size,
                              hipStream_t stream) {
  const float* Q = (const float*)d_in[0];
  const float* K = (const float*)d_in[1];
  const float* V = (const float*)d_in[2];
  const int*   M = (const int*)d_in[3];
  float* O = (float*)d_out;

  unsigned short* Kw = (unsigned short*)d_ws;                 // 16.78 MB
  unsigned short* Vw = Kw + (size_t)4 * 16 * S * D;           // 16.78 MB (V^T)

  dim3 cgrid(NT, 4 * 16);
  hipLaunchKernelGGL(cvt_kv, cgrid, dim3(256), 0, stream, K, V, Kw, Vw);

  dim3 grid(S / BQ, 4 * 16);
  hipLaunchKernelGGL(attn_fwd, grid, dim3(256), 0, stream, Q, Kw, Vw, M, O);
}

// Round 17
// 271.008 us; speedup vs baseline: 1.3192x; 1.0976x over previous
//
#include <hip/hip_runtime.h>

namespace {

constexpr int D  = 64;
constexpr int S  = 2048;
constexpr int BQ = 64;    // q rows per block (4 waves x 16)
constexpr int BK = 64;    // kv rows per tile
constexpr int NT = S / BK;
constexpr float SCALE = 0.125f;  // 1/sqrt(64)
constexpr int PP = 72;    // LDS pitch for P (bf16 elems)
constexpr int MPB = 68;   // mask LDS row pitch in bytes (17 banks, coprime to 32)

typedef short s16x8 __attribute__((ext_vector_type(8)));
typedef float f32x4 __attribute__((ext_vector_type(4)));

__device__ inline unsigned cvt_pk_bf16(float a, float b) {   // lo=bf16(a), hi=bf16(b), RNE
  unsigned r;
  asm("v_cvt_pk_bf16_f32 %0, %1, %2" : "=v"(r) : "v"(a), "v"(b));
  return r;
}

__device__ inline unsigned short f2bf(float f) {
  union { float f; unsigned u; } v; v.f = f;
  unsigned u = v.u + (0x7fffu + ((v.u >> 16) & 1u));  // RNE
  return (unsigned short)(u >> 16);
}

// ---- one-shot: K -> bf16 [bh][k][d]; V -> bf16 transposed [bh][d][k] ----
__global__ __launch_bounds__(256)
void cvt_kv(const float* __restrict__ Kg, const float* __restrict__ Vg,
            unsigned short* __restrict__ Kw, unsigned short* __restrict__ Vw)
{
  __shared__ unsigned short vt[64 * 72];
  const int tid = threadIdx.x;
  const int kt = blockIdx.x, bh = blockIdx.y;
  const int k0 = kt * BK;

  #pragma unroll
  for (int i = 0; i < 4; ++i) {
    const int e4 = i * 256 + tid;
    const int r  = e4 >> 4;          // kv row within tile 0..63
    const int db = (e4 & 15) * 4;    // d base 0..60
    const size_t rowK = (size_t)bh * S + k0 + r;

    const float4 kf = *(const float4*)(Kg + rowK * D + db);
    const float4 vf = *(const float4*)(Vg + rowK * D + db);

    uint2 kk;
    kk.x = cvt_pk_bf16(kf.x, kf.y);
    kk.y = cvt_pk_bf16(kf.z, kf.w);
    *(uint2*)&Kw[rowK * D + db] = kk;   // coalesced, logical layout

    const unsigned v01 = cvt_pk_bf16(vf.x, vf.y);
    const unsigned v23 = cvt_pk_bf16(vf.z, vf.w);
    vt[(db + 0) * 72 + r] = (unsigned short)(v01);
    vt[(db + 1) * 72 + r] = (unsigned short)(v01 >> 16);
    vt[(db + 2) * 72 + r] = (unsigned short)(v23);
    vt[(db + 3) * 72 + r] = (unsigned short)(v23 >> 16);
  }
  __syncthreads();

  const int d  = tid >> 2;          // 0..63
  const int bq = (tid & 3) * 16;    // 16 ushorts per thread
  const uint4 a = *(const uint4*)&vt[d * 72 + bq];
  const uint4 b = *(const uint4*)&vt[d * 72 + bq + 8];
  unsigned short* vrow = Vw + ((size_t)bh * D + d) * S + k0 + bq;
  *(uint4*)(vrow)     = a;
  *(uint4*)(vrow + 8) = b;
}

// ---- main attention (R9 base; delta: coalesced mask loads + LDS redistribution) ----
__global__ __launch_bounds__(256, 4)
void attn_fwd(const float* __restrict__ Qg,
              const unsigned short* __restrict__ Kw,
              const unsigned short* __restrict__ Vw,
              const int* __restrict__ Mg,
              float* __restrict__ Og)
{
  __shared__ unsigned short k_lds[BK * 64];     // [k][d] bf16, 16B-blocks XOR-swizzled by (k&7)
  __shared__ unsigned short vt_lds[D * 64];     // [d][k] bf16, swizzled by (d&7)
  __shared__ unsigned short p_lds[4 * 16 * PP]; // per-wave P [q16][k64]
  __shared__ unsigned char  m_lds[BQ * MPB];    // mask tile as bytes, pitch 68

  const int tid  = threadIdx.x;
  const int lane = tid & 63;
  const int w    = tid >> 6;
  const int g    = lane >> 4;
  const int lq   = lane & 15;

  const int q0 = blockIdx.x * BQ;
  const int bh = blockIdx.y;

  const float* Qb = Qg + (size_t)bh * S * D;
  float* Ob = Og + (size_t)bh * S * D;
  const unsigned short* Kb = Kw + (size_t)bh * S * D;
  const unsigned short* Vb = Vw + (size_t)bh * D * S;

  // coalesced mask source: pass i covers row q0 + i*16 + (tid>>4), cols (tid&15)*4..+3
  // per wave-instruction: 4 rows x 256B contiguous segments
  const int mrow = tid >> 4;           // 0..15
  const int mcol = (tid & 15) * 4;     // 0..60
  const int* Msrc = Mg + ((size_t)bh * S + q0 + mrow) * S + mcol;

  // staging assignment: thread -> row sr (0..63), block pair sb (0,2,4,6)
  const int sr  = tid >> 2;
  const int sb  = (tid & 3) * 2;
  const int swz = sr & 7;
  const unsigned short* Ksrc0 = Kb + (size_t)sr * D + sb * 8;          // + k0*64 per tile
  const unsigned short* Vsrc0 = Vb + (size_t)sr * S + sb * 8;          // + k0 per tile

  // Q fragments (B-operand): q = q0+w*16+lq, d = ks*32+g*8+j; scale folded in
  s16x8 qf[2];
  {
    const float* qr = Qb + (size_t)(q0 + w * 16 + lq) * D;
    #pragma unroll
    for (int ks = 0; ks < 2; ++ks) {
      float4 a = *(const float4*)(qr + ks * 32 + g * 8);
      float4 b = *(const float4*)(qr + ks * 32 + g * 8 + 4);
      s16x8 t;
      t[0] = (short)f2bf(a.x * SCALE); t[1] = (short)f2bf(a.y * SCALE);
      t[2] = (short)f2bf(a.z * SCALE); t[3] = (short)f2bf(a.w * SCALE);
      t[4] = (short)f2bf(b.x * SCALE); t[5] = (short)f2bf(b.y * SCALE);
      t[6] = (short)f2bf(b.z * SCALE); t[7] = (short)f2bf(b.w * SCALE);
      qf[ks] = t;
    }
  }

  f32x4 o[4];
  #pragma unroll
  for (int i = 0; i < 4; ++i) { o[i][0]=0.f; o[i][1]=0.f; o[i][2]=0.f; o[i][3]=0.f; }
  float m_run = -INFINITY, l_run = 0.f;

  unsigned short* p_w = p_lds + w * 16 * PP;
  const int swzr = lq & 7;   // read-side swizzle (rows step by 16 so row&7 == lq&7)

  // ---- prologue: tile-0 KV staging regs + tile-0 mask regs ----
  uint4 ka = *(const uint4*)(Ksrc0);
  uint4 kb = *(const uint4*)(Ksrc0 + 8);
  uint4 va = *(const uint4*)(Vsrc0);
  uint4 vb = *(const uint4*)(Vsrc0 + 8);
  uint4 mr[4];
  #pragma unroll
  for (int i = 0; i < 4; ++i) mr[i] = *(const uint4*)(Msrc + (size_t)(i * 16) * S);

  for (int kt = 0; kt < NT; ++kt) {
    // ---- write-late: KV regs + mask bytes (staged one full tile ago) -> LDS ----
    *(uint4*)&k_lds [sr * 64 + ((sb    ) ^ swz) * 8] = ka;
    *(uint4*)&k_lds [sr * 64 + ((sb + 1) ^ swz) * 8] = kb;
    *(uint4*)&vt_lds[sr * 64 + ((sb    ) ^ swz) * 8] = va;
    *(uint4*)&vt_lds[sr * 64 + ((sb + 1) ^ swz) * 8] = vb;
    #pragma unroll
    for (int i = 0; i < 4; ++i) {
      const unsigned pk = (mr[i].x ? 1u : 0u)        | (mr[i].y ? 0x100u : 0u) |
                          (mr[i].z ? 0x10000u : 0u)  | (mr[i].w ? 0x1000000u : 0u);
      *(unsigned*)&m_lds[(i * 16 + mrow) * MPB + mcol] = pk;
    }

    // barrier-1 (write->read): drain LDS only, NOT vmem
    asm volatile("s_waitcnt lgkmcnt(0)" ::: "memory");
    __builtin_amdgcn_sched_barrier(0);
    __builtin_amdgcn_s_barrier();

    // ---- issue-early: tile kt+1 KV + mask loads; land during this tile's compute ----
    const int kn = (kt + 1 < NT) ? (kt + 1) * BK : kt * BK;
    uint4 kan = *(const uint4*)(Ksrc0 + (size_t)kn * 64);
    uint4 kbn = *(const uint4*)(Ksrc0 + (size_t)kn * 64 + 8);
    uint4 van = *(const uint4*)(Vsrc0 + kn);
    uint4 vbn = *(const uint4*)(Vsrc0 + kn + 8);
    uint4 mrn[4];
    #pragma unroll
    for (int i = 0; i < 4; ++i) mrn[i] = *(const uint4*)(Msrc + (size_t)(i * 16) * S + kn);

    // ---- S^T = K . Q^T  (C[k][q]) ----
    f32x4 st[4];
    #pragma unroll
    for (int t = 0; t < 4; ++t) {
      f32x4 c; c[0]=0.f; c[1]=0.f; c[2]=0.f; c[3]=0.f;
      #pragma unroll
      for (int ks = 0; ks < 2; ++ks) {
        s16x8 a = *(const s16x8*)&k_lds[(16 * t + lq) * 64 + (((ks << 2) + g) ^ swzr) * 8];
        c = __builtin_amdgcn_mfma_f32_16x16x32_bf16(a, qf[ks], c, 0, 0, 0);
      }
      st[t] = c;
    }

    // ---- mask (from LDS bytes) + online softmax; lane owns q=w*16+lq, k=16t+4g+r ----
    float mx = -INFINITY;
    #pragma unroll
    for (int t = 0; t < 4; ++t) {
      const unsigned mb = *(const unsigned*)&m_lds[(w * 16 + lq) * MPB + 16 * t + 4 * g];
      if (mb & 0xFFu)        st[t][0] = -1e9f;
      if (mb & 0xFF00u)      st[t][1] = -1e9f;
      if (mb & 0xFF0000u)    st[t][2] = -1e9f;
      if (mb & 0xFF000000u)  st[t][3] = -1e9f;
      mx = fmaxf(mx, fmaxf(fmaxf(st[t][0], st[t][1]), fmaxf(st[t][2], st[t][3])));
    }
    mx = fmaxf(mx, __shfl_xor(mx, 16));
    mx = fmaxf(mx, __shfl_xor(mx, 32));
    const float m_new = fmaxf(m_run, mx);
    const float alpha = __expf(m_run - m_new);
    float rs = 0.f;
    #pragma unroll
    for (int t = 0; t < 4; ++t) {
      #pragma unroll
      for (int r = 0; r < 4; ++r) {
        float p = __expf(st[t][r] - m_new);
        st[t][r] = p;
        rs += p;
      }
    }
    rs += __shfl_xor(rs, 16);
    rs += __shfl_xor(rs, 32);
    l_run = l_run * alpha + rs;
    m_run = m_new;

    const float al0 = __shfl(alpha, 4 * g + 0);
    const float al1 = __shfl(alpha, 4 * g + 1);
    const float al2 = __shfl(alpha, 4 * g + 2);
    const float al3 = __shfl(alpha, 4 * g + 3);
    #pragma unroll
    for (int dt = 0; dt < 4; ++dt) {
      o[dt][0] *= al0; o[dt][1] *= al1; o[dt][2] *= al2; o[dt][3] *= al3;
    }

    // ---- P -> per-wave LDS (bf16 via cvt_pk) ----
    #pragma unroll
    for (int t = 0; t < 4; ++t) {
      uint2 pk;
      pk.x = cvt_pk_bf16(st[t][0], st[t][1]);
      pk.y = cvt_pk_bf16(st[t][2], st[t][3]);
      *(uint2*)&p_w[lq * PP + 16 * t + 4 * g] = pk;
    }
    asm volatile("s_waitcnt lgkmcnt(0)" ::: "memory");  // wave-local P RAW
    __builtin_amdgcn_sched_barrier(0);

    // ---- O += P . V ----
    const s16x8 pa0 = *(const s16x8*)&p_w[lq * PP + 0  + g * 8];
    const s16x8 pa1 = *(const s16x8*)&p_w[lq * PP + 32 + g * 8];
    #pragma unroll
    for (int dt = 0; dt < 4; ++dt) {
      s16x8 vb0 = *(const s16x8*)&vt_lds[(16 * dt + lq) * 64 + ((g    ) ^ swzr) * 8];
      s16x8 vb1 = *(const s16x8*)&vt_lds[(16 * dt + lq) * 64 + ((4 + g) ^ swzr) * 8];
      o[dt] = __builtin_amdgcn_mfma_f32_16x16x32_bf16(pa0, vb0, o[dt], 0, 0, 0);
      o[dt] = __builtin_amdgcn_mfma_f32_16x16x32_bf16(pa1, vb1, o[dt], 0, 0, 0);
    }

    // barrier-2 (read->write WAR before next iter's ds_write)
    __builtin_amdgcn_s_barrier();

    ka = kan; kb = kbn; va = van; vb = vbn;
    #pragma unroll
    for (int i = 0; i < 4; ++i) mr[i] = mrn[i];
  }

  // ---- epilogue ----
  const float linv = 1.0f / l_run;
  const float li0 = __shfl(linv, 4 * g + 0);
  const float li1 = __shfl(linv, 4 * g + 1);
  const float li2 = __shfl(linv, 4 * g + 2);
  const float li3 = __shfl(linv, 4 * g + 3);
  #pragma unroll
  for (int dt = 0; dt < 4; ++dt) {
    const int d = 16 * dt + lq;
    Ob[(size_t)(q0 + w * 16 + 4 * g + 0) * D + d] = o[dt][0] * li0;
    Ob[(size_t)(q0 + w * 16 + 4 * g + 1) * D + d] = o[dt][1] * li1;
    Ob[(size_t)(q0 + w * 16 + 4 * g + 2) * D + d] = o[dt][2] * li2;
    Ob[(size_t)(q0 + w * 16 + 4 * g + 3) * D + d] = o[dt][3] * li3;
  }
}

} // namespace

extern "C" void kernel_launch(void* const* d_in, const int* in_sizes, int n_in,
                              void* d_out, int out_size, void* d_ws, size_t ws_size,
                              hipStream_t stream) {
  const float* Q = (const float*)d_in[0];
  const float* K = (const float*)d_in[1];
  const float* V = (const float*)d_in[2];
  const int*   M = (const int*)d_in[3];
  float* O = (float*)d_out;

  unsigned short* Kw = (unsigned short*)d_ws;                 // 16.78 MB
  unsigned short* Vw = Kw + (size_t)4 * 16 * S * D;           // 16.78 MB (V^T)

  dim3 cgrid(NT, 4 * 16);
  hipLaunchKernelGGL(cvt_kv, cgrid, dim3(256), 0, stream, K, V, Kw, Vw);

  dim3 grid(S / BQ, 4 * 16);
  hipLaunchKernelGGL(attn_fwd, grid, dim3(256), 0, stream, Q, Kw, Vw, M, O);
}